// Round 8
// baseline (80.120 us; speedup 1.0000x reference)
//
#include <hip/hip_runtime.h>

// Round 8: DIAGNOSTIC. Exact R7 kernel (rolling z-strip of 4, y-sort ->
// z-sort -> band-stat prune -> antichain exclusions -> triple forgetful;
// absmax 0.0 R1-R7) wrapped in a runtime rep-loop (rep=3) so the dispatch
// exceeds the harness fill dispatches (~44 us) and surfaces in the rocprof
// top-5, exposing VGPR_Count / OccupancyPercent / VALUBusy for the real
// code path. Stores are idempotent -> output unchanged. Revert next round.

#define MIN3(a, b, c) fminf(fminf(a, b), c)
#define MAX3(a, b, c) fmaxf(fmaxf(a, b), c)
#define MED3(a, b, c) __builtin_amdgcn_fmed3f(a, b, c)

__device__ __forceinline__ void sort3(float &a, float &b, float &c) {
    float lo = MIN3(a, b, c);
    float hi = MAX3(a, b, c);
    float md = MED3(a, b, c);
    a = lo; b = md; c = hi;
}

__device__ __forceinline__ float sel19(const float V[9][6], int o) {
    float a0h = MAX3(V[0][o], V[0][o + 1], V[0][o + 2]);
    float a1m = MED3(V[1][o], V[1][o + 1], V[1][o + 2]);
    float a1h = MAX3(V[1][o], V[1][o + 1], V[1][o + 2]);
    float a2l = V[2][o], a2m = V[2][o + 1], a2h = V[2][o + 2];
    sort3(a2l, a2m, a2h);
    float b0m = MED3(V[3][o], V[3][o + 1], V[3][o + 2]);
    float b0h = MAX3(V[3][o], V[3][o + 1], V[3][o + 2]);
    float b1l = V[4][o], b1m = V[4][o + 1], b1h = V[4][o + 2];
    sort3(b1l, b1m, b1h);
    float b2l = MIN3(V[5][o], V[5][o + 1], V[5][o + 2]);
    float b2m = MED3(V[5][o], V[5][o + 1], V[5][o + 2]);
    float c0l = V[6][o], c0m = V[6][o + 1], c0h = V[6][o + 2];
    sort3(c0l, c0m, c0h);
    float c1l = MIN3(V[7][o], V[7][o + 1], V[7][o + 2]);
    float c1m = MED3(V[7][o], V[7][o + 1], V[7][o + 2]);
    float c2l = MIN3(V[8][o], V[8][o + 1], V[8][o + 2]);

    float pa = a1m, pb = b0m, pc = b1l; sort3(pa, pb, pc);  // pa <= med
    float qa = b1h, qb = b2m, qc = c1m; sort3(qa, qb, qc);  // qc >= med
    float ra = a0h, rb = a2l, rc = c0l; sort3(ra, rb, rc);  // ra <= med
    float sa = a2h, sb = c0h, sc = c2l; sort3(sa, sb, sc);  // sc >= med
    (void)pa; (void)qc; (void)ra; (void)sc;

    float t1l = pb, t1m = pc, t1h = b1m;
    float t2l = rb, t2m = rc, t2h = a1h; sort3(t2l, t2m, t2h);
    float t3l = sa, t3m = sb, t3h = c1l; sort3(t3l, t3m, t3h);
    {
        float lam1 = MED3(t1l, t2l, t3l), lam2 = MAX3(t1l, t2l, t3l);
        float eta1 = MIN3(t1h, t2h, t3h), eta2 = MED3(t1h, t2h, t3h);
        float mu1 = t1m, mu2 = t2m, mu3 = t3m;
        t1l = lam1; t1m = lam2; t1h = qa; sort3(t1l, t1m, t1h);
        t2l = mu1;  t2m = mu2;  t2h = mu3; sort3(t2l, t2m, t2h);
        t3l = eta1; t3m = eta2; t3h = qb; sort3(t3l, t3m, t3h);
    }
    {
        float lam1 = MED3(t1l, t2l, t3l), lam2 = MAX3(t1l, t2l, t3l);
        float eta1 = MIN3(t1h, t2h, t3h), eta2 = MED3(t1h, t2h, t3h);
        float mu1 = t1m, mu2 = t2m, mu3 = t3m;
        t1l = lam1; t1m = lam2; t1h = a2m; sort3(t1l, t1m, t1h);
        t2l = mu1;  t2m = mu2;  t2h = mu3; sort3(t2l, t2m, t2h);
        t3l = eta1; t3m = eta2; t3h = c0m; sort3(t3l, t3m, t3h);
    }
    {
        float lam1 = MED3(t1l, t2l, t3l), lam2 = MAX3(t1l, t2l, t3l);
        float eta1 = MIN3(t1h, t2h, t3h), eta2 = MED3(t1h, t2h, t3h);
        float mu1 = t1m, mu2 = t2m, mu3 = t3m;
        t1l = lam1; t1m = lam2; t1h = b0h; sort3(t1l, t1m, t1h);
        t2l = mu1;  t2m = mu2;  t2h = mu3; sort3(t2l, t2m, t2h);
        t3l = eta1; t3m = eta2; t3h = b2l; sort3(t3l, t3m, t3h);
    }
    return MED3(MAX3(t1l, t2l, t3l), MED3(t1m, t2m, t3m),
                MIN3(t1h, t2h, t3h));
}

__global__ __launch_bounds__(256) void median3d_kernel(
    const float *__restrict__ x, float *__restrict__ out, int rep) {
    const int W = 256, H = 256, D = 64;
    const int lane = threadIdx.x;
    const int w0 = lane << 2;
    const int h = blockIdx.y * 4 + threadIdx.y;
    const int d0 = blockIdx.z * 4;
    const int wl = (lane == 0) ? 0 : (w0 - 1);
    const int wr = (lane == 63) ? (W - 1) : (w0 + 4);
    const bool lval = (lane != 0), rval = (lane != 63);

    for (int it = 0; it < rep; ++it) {
        float Yst[3][3][6];

#define LOADPLANE(P, SLOT)                                                   \
    do {                                                                     \
        const int dd = d0 + (P)-1;                                           \
        const bool zok = (unsigned)dd < (unsigned)D;                         \
        const int dc = zok ? dd : 0;                                         \
        float r[3][6];                                                       \
        _Pragma("unroll") for (int dy = 0; dy < 3; ++dy) {                   \
            const int hh = h + dy - 1;                                       \
            const bool hok = (unsigned)hh < (unsigned)H;                     \
            const int hc = hok ? hh : 0;                                     \
            const bool ok = zok && hok;                                      \
            const float *rowp = x + (size_t)(dc * H + hc) * W;               \
            const float l = rowp[wl];                                        \
            const float4 m = *(const float4 *)(rowp + w0);                   \
            const float rr = rowp[wr];                                       \
            r[dy][0] = (ok && lval) ? l : 0.0f;                              \
            r[dy][1] = ok ? m.x : 0.0f;                                      \
            r[dy][2] = ok ? m.y : 0.0f;                                      \
            r[dy][3] = ok ? m.z : 0.0f;                                      \
            r[dy][4] = ok ? m.w : 0.0f;                                      \
            r[dy][5] = (ok && rval) ? rr : 0.0f;                             \
        }                                                                    \
        _Pragma("unroll") for (int c = 0; c < 6; ++c) {                      \
            sort3(r[0][c], r[1][c], r[2][c]);                                \
            Yst[SLOT][0][c] = r[0][c];                                       \
            Yst[SLOT][1][c] = r[1][c];                                       \
            Yst[SLOT][2][c] = r[2][c];                                       \
        }                                                                    \
    } while (0)

        LOADPLANE(0, 0);
        LOADPLANE(1, 1);

#pragma unroll
        for (int zo = 0; zo < 4; ++zo) {
            switch ((zo + 2) % 3) {
                case 0: LOADPLANE(zo + 2, 0); break;
                case 1: LOADPLANE(zo + 2, 1); break;
                default: LOADPLANE(zo + 2, 2); break;
            }
            const int sA = zo % 3, sB = (zo + 1) % 3, sC = (zo + 2) % 3;
            float V[9][6];
#pragma unroll
            for (int yr = 0; yr < 3; ++yr)
#pragma unroll
                for (int c = 0; c < 6; ++c) {
                    float a = Yst[sA][yr][c];
                    float b = Yst[sB][yr][c];
                    float cc = Yst[sC][yr][c];
                    sort3(a, b, cc);
                    V[0 + yr][c] = a;
                    V[3 + yr][c] = b;
                    V[6 + yr][c] = cc;
                }
            float4 r4;
            r4.x = sel19(V, 0);
            r4.y = sel19(V, 1);
            r4.z = sel19(V, 2);
            r4.w = sel19(V, 3);
            *(float4 *)(out + (size_t)((d0 + zo) * H + h) * W + w0) = r4;
        }
#undef LOADPLANE
    }
}

extern "C" void kernel_launch(void *const *d_in, const int *in_sizes, int n_in,
                              void *d_out, int out_size, void *d_ws,
                              size_t ws_size, hipStream_t stream) {
    const float *x = (const float *)d_in[0];
    float *out = (float *)d_out;
    dim3 block(64, 4, 1);
    dim3 grid(1, 256 / 4, 64 / 4);
    median3d_kernel<<<grid, block, 0, stream>>>(x, out, 3);
}